// Round 1
// baseline (888.930 us; speedup 1.0000x reference)
//
#include <hip/hip_runtime.h>

// Spatially varying anisotropic 2D elastic wave simulator, 384x384, 192 steps.
// Round 0: correctness baseline. 1 setup kernel + 192 step kernels (ping-pong
// buffers), one launch per time step. Coefficients pre-scaled by dt^2*hinv2/rho.

#define NXg 384
#define NYg 384
#define NPT (NXg * NYg)
#define NTs 192
#define NFRAMES 48

// physical constants
#define H_       1e-4
#define DT_      5e-9
#define RHO_     1610.0

// clip bounds
#define B11_LO 5e10f
#define B11_HI 2.5e11f
#define B22_LO 5e9f
#define B22_HI 5e10f
#define B12_LO 5e9f
#define B12_HI 5e10f
#define B16_LO 0.0f
#define B16_HI 6e10f
#define B26_LO 0.0f
#define B26_HI 2e10f
#define B66_LO 5e9f
#define B66_HI 3e10f

// dt^2 * (1/h^2) / rho  — folded into coefficient fields
// dt^2 = 2.5e-17, 1/h^2 = 1e8, /1610
static __device__ __constant__ float kScale  = (float)(DT_ * DT_ / (H_ * H_) / RHO_);
static __device__ __constant__ float kSrcScl = (float)(DT_ * DT_ / RHO_);

__device__ __forceinline__ float ld0(const float* __restrict__ u, int x, int y) {
    // zero (fixed) boundary via zero-padding semantics
    if ((unsigned)x >= (unsigned)NXg || (unsigned)y >= (unsigned)NYg) return 0.0f;
    return u[x * NYg + y];
}

__device__ __forceinline__ float clipf(float v, float lo, float hi) {
    return fminf(fmaxf(v, lo), hi);
}

__global__ __launch_bounds__(256)
void setup_kernel(const float* __restrict__ lc11, const float* __restrict__ lc12,
                  const float* __restrict__ lc16, const float* __restrict__ lc22,
                  const float* __restrict__ lc26, const float* __restrict__ lc66,
                  const float* __restrict__ gauss, float* __restrict__ ws) {
    int i = blockIdx.x * blockDim.x + threadIdx.x;
    if (i >= NPT) return;
    float C11 = clipf(expf(lc11[i]), B11_LO, B11_HI);
    float C12 = clipf(expf(lc12[i]), B12_LO, B12_HI);
    float C16 = clipf(expf(lc16[i]), B16_LO, B16_HI);
    float C22 = clipf(expf(lc22[i]), B22_LO, B22_HI);
    float C26 = clipf(expf(lc26[i]), B26_LO, B26_HI);
    float C66 = clipf(expf(lc66[i]), B66_LO, B66_HI);
    float s = kScale;
    ws[0 * NPT + i] = C11 * s;          // A11
    ws[1 * NPT + i] = C22 * s;          // A22
    ws[2 * NPT + i] = (C12 + C66) * s;  // A12p66
    ws[3 * NPT + i] = C16 * s;          // A16
    ws[4 * NPT + i] = C26 * s;          // A26
    ws[5 * NPT + i] = C66 * s;          // A66
    ws[6 * NPT + i] = gauss[i] * kSrcScl; // GS
    // zero-init state (ws is poisoned 0xAA before every timed call)
    ws[7 * NPT + i]  = 0.0f;  // uxP
    ws[8 * NPT + i]  = 0.0f;  // uyP
    ws[9 * NPT + i]  = 0.0f;  // uxQ
    ws[10 * NPT + i] = 0.0f;  // uyQ
}

__global__ __launch_bounds__(256)
void step_kernel(const float* __restrict__ uxc, const float* __restrict__ uyc,
                 float* __restrict__ uxo, float* __restrict__ uyo,
                 const float* __restrict__ ws, const float* __restrict__ sig,
                 int t, float* __restrict__ out_ux, float* __restrict__ out_uy) {
    int y = blockIdx.x * blockDim.x + threadIdx.x;  // fastest dim, coalesced
    int x = blockIdx.y * blockDim.y + threadIdx.y;
    int i = x * NYg + y;

    float sig_t = sig[t];

    // ux neighborhood
    float xc  = uxc[i];
    float xxm = ld0(uxc, x - 1, y);
    float xxp = ld0(uxc, x + 1, y);
    float xym = ld0(uxc, x, y - 1);
    float xyp = ld0(uxc, x, y + 1);
    float xmm = ld0(uxc, x - 1, y - 1);
    float xmp = ld0(uxc, x - 1, y + 1);
    float xpm = ld0(uxc, x + 1, y - 1);
    float xpp = ld0(uxc, x + 1, y + 1);
    // uy neighborhood
    float yc  = uyc[i];
    float yxm = ld0(uyc, x - 1, y);
    float yxp = ld0(uyc, x + 1, y);
    float yym = ld0(uyc, x, y - 1);
    float yyp = ld0(uyc, x, y + 1);
    float ymm = ld0(uyc, x - 1, y - 1);
    float ymp = ld0(uyc, x - 1, y + 1);
    float ypm = ld0(uyc, x + 1, y - 1);
    float ypp = ld0(uyc, x + 1, y + 1);

    // stencil sums (hinv2 pre-folded into coefficients)
    float cxx_x = xxm + xxp - 2.0f * xc;
    float cyy_x = xym + xyp - 2.0f * xc;
    float cxy_x = 0.25f * (xmm - xmp - xpm + xpp);
    float cxx_y = yxm + yxp - 2.0f * yc;
    float cyy_y = yym + yyp - 2.0f * yc;
    float cxy_y = 0.25f * (ymm - ymp - ypm + ypp);

    float a11    = ws[0 * NPT + i];
    float a22    = ws[1 * NPT + i];
    float a12p66 = ws[2 * NPT + i];
    float a16    = ws[3 * NPT + i];
    float a26    = ws[4 * NPT + i];
    float a66    = ws[5 * NPT + i];
    float gs     = ws[6 * NPT + i];

    float lux = a11 * cxx_x + a66 * cyy_x + a12p66 * cxy_y
              + 2.0f * a16 * cxy_x + a16 * cxx_y + a26 * cyy_y;
    float luy = a66 * cxx_y + a22 * cyy_y + a12p66 * cxy_x
              + a16 * cxx_x + a26 * cyy_x + 2.0f * a26 * cxy_y;

    float ux_new = 2.0f * xc - uxo[i] + lux;
    float uy_new = 2.0f * yc - uyo[i] + luy + sig_t * gs;

    uxo[i] = ux_new;  // in-place overwrite of t-2 buffer (only center-read)
    uyo[i] = uy_new;

    if (out_ux != nullptr) {
        out_ux[i] = ux_new;
        out_uy[i] = uy_new;
    }
}

extern "C" void kernel_launch(void* const* d_in, const int* in_sizes, int n_in,
                              void* d_out, int out_size, void* d_ws, size_t ws_size,
                              hipStream_t stream) {
    const float* lc11  = (const float*)d_in[0];
    const float* lc12  = (const float*)d_in[1];
    const float* lc16  = (const float*)d_in[2];
    const float* lc22  = (const float*)d_in[3];
    const float* lc26  = (const float*)d_in[4];
    const float* lc66  = (const float*)d_in[5];
    const float* gauss = (const float*)d_in[6];
    const float* sig   = (const float*)d_in[7];

    float* ws  = (float*)d_ws;
    float* out = (float*)d_out;

    setup_kernel<<<(NPT + 255) / 256, 256, 0, stream>>>(lc11, lc12, lc16, lc22,
                                                        lc26, lc66, gauss, ws);

    float* uxP = ws + 7 * NPT;
    float* uyP = ws + 8 * NPT;
    float* uxQ = ws + 9 * NPT;
    float* uyQ = ws + 10 * NPT;

    dim3 blk(128, 2);
    dim3 grd(NYg / 128, NXg / 2);

    for (int t = 0; t < NTs; ++t) {
        const float *uxc, *uyc;
        float *uxo, *uyo;
        if ((t & 1) == 0) { uxc = uxP; uyc = uyP; uxo = uxQ; uyo = uyQ; }
        else              { uxc = uxQ; uyc = uyQ; uxo = uxP; uyo = uyP; }
        float* oux = nullptr;
        float* ouy = nullptr;
        if ((t & 3) == 3) {
            int f = t >> 2;
            oux = out + (size_t)f * NPT;
            ouy = out + (size_t)(NFRAMES + f) * NPT;
        }
        step_kernel<<<grd, blk, 0, stream>>>(uxc, uyc, uxo, uyo, ws, sig, t, oux, ouy);
    }
}

// Round 2
// 476.853 us; speedup vs baseline: 1.8642x; 1.8642x over previous
//
#include <hip/hip_runtime.h>

// Spatially varying anisotropic 2D elastic wave sim, 384x384, 192 steps.
// Round 1: time-tiled trapezoid fusion. K=12 steps per launch, 16 fused
// launches + 1 setup. Each block: 24x24 owned tile + 12 halo = 48x48 staging,
// state held in per-thread registers (3x3 patch/thread), LDS used only as the
// per-step neighbor-exchange surface. Coefficients (pre-scaled by
// dt^2*hinv2/rho) cached in VGPRs for the whole launch.

#define NXg 384
#define NYg 384
#define NPT (NXg * NYg)
#define NTs 192
#define NFRAMES 48

#define OWN 24        // owned tile edge
#define HALO 12       // halo width == fused steps
#define TS 48         // staging edge = OWN + 2*HALO
#define KSTEPS 12
#define NLAUNCH 16    // 192 / 12

#define H_   1e-4
#define DT_  5e-9
#define RHO_ 1610.0

#define B11_LO 5e10f
#define B11_HI 2.5e11f
#define B22_LO 5e9f
#define B22_HI 5e10f
#define B12_LO 5e9f
#define B12_HI 5e10f
#define B16_LO 0.0f
#define B16_HI 6e10f
#define B26_LO 0.0f
#define B26_HI 2e10f
#define B66_LO 5e9f
#define B66_HI 3e10f

static __device__ __constant__ float kScale  = (float)(DT_ * DT_ / (H_ * H_) / RHO_);
static __device__ __constant__ float kSrcScl = (float)(DT_ * DT_ / RHO_);

__device__ __forceinline__ float clipf(float v, float lo, float hi) {
    return fminf(fmaxf(v, lo), hi);
}

// ws float layout: 7 coeff arrays, then 2 ping-pong state sets of 4 arrays.
// [0]=A11 [1]=A22 [2]=A12p66 [3]=A16 [4]=A26 [5]=A66 [6]=GS
// set0: [7]=CX [8]=CY [9]=OX [10]=OY     set1: [11..14]

__global__ __launch_bounds__(256)
void setup_kernel(const float* __restrict__ lc11, const float* __restrict__ lc12,
                  const float* __restrict__ lc16, const float* __restrict__ lc22,
                  const float* __restrict__ lc26, const float* __restrict__ lc66,
                  const float* __restrict__ gauss, float* __restrict__ ws) {
    int i = blockIdx.x * blockDim.x + threadIdx.x;
    if (i >= NPT) return;
    float C11 = clipf(expf(lc11[i]), B11_LO, B11_HI);
    float C12 = clipf(expf(lc12[i]), B12_LO, B12_HI);
    float C16 = clipf(expf(lc16[i]), B16_LO, B16_HI);
    float C22 = clipf(expf(lc22[i]), B22_LO, B22_HI);
    float C26 = clipf(expf(lc26[i]), B26_LO, B26_HI);
    float C66 = clipf(expf(lc66[i]), B66_LO, B66_HI);
    float s = kScale;
    ws[0 * NPT + i] = C11 * s;
    ws[1 * NPT + i] = C22 * s;
    ws[2 * NPT + i] = (C12 + C66) * s;
    ws[3 * NPT + i] = C16 * s;
    ws[4 * NPT + i] = C26 * s;
    ws[5 * NPT + i] = C66 * s;
    ws[6 * NPT + i] = gauss[i] * kSrcScl;
    // zero-init state set 0 (launch 0 reads it); ws is poisoned every call
    ws[7 * NPT + i]  = 0.0f;
    ws[8 * NPT + i]  = 0.0f;
    ws[9 * NPT + i]  = 0.0f;
    ws[10 * NPT + i] = 0.0f;
}

__global__ __launch_bounds__(256, 1)
void fused_kernel(const float* __restrict__ ws, const float* __restrict__ sig,
                  const float* __restrict__ inCX, const float* __restrict__ inCY,
                  const float* __restrict__ inOX, const float* __restrict__ inOY,
                  float* __restrict__ outCX, float* __restrict__ outCY,
                  float* __restrict__ outOX, float* __restrict__ outOY,
                  float* __restrict__ out, int L) {
    __shared__ float sx[TS][TS + 1];
    __shared__ float sy[TS][TS + 1];

    const int tid = threadIdx.x;
    const int tx = tid >> 4;          // 0..15, row group
    const int ty = tid & 15;          // 0..15, col group
    const int r0 = 3 * tx;            // staging row base
    const int c0 = 3 * ty;            // staging col base
    const int gx0 = blockIdx.y * OWN - HALO;
    const int gy0 = blockIdx.x * OWN - HALO;

    // per-point registers (p = i*3+j)
    float cx[9], cy[9], ox[9], oy[9];
    float a11[9], a22[9], a12p66[9], a16[9], a26[9], a66[9], gs[9];
    bool  dom[9];
    int   gidx[9];

#pragma unroll
    for (int i = 0; i < 3; ++i) {
#pragma unroll
        for (int j = 0; j < 3; ++j) {
            int p = i * 3 + j;
            int gx = gx0 + r0 + i;
            int gy = gy0 + c0 + j;
            bool d = (unsigned)gx < (unsigned)NXg && (unsigned)gy < (unsigned)NYg;
            int g = d ? gx * NYg + gy : 0;
            dom[p] = d; gidx[p] = g;
            cx[p] = d ? inCX[g] : 0.0f;
            cy[p] = d ? inCY[g] : 0.0f;
            ox[p] = d ? inOX[g] : 0.0f;
            oy[p] = d ? inOY[g] : 0.0f;
            a11[p]    = d ? ws[0 * NPT + g] : 0.0f;
            a22[p]    = d ? ws[1 * NPT + g] : 0.0f;
            a12p66[p] = d ? ws[2 * NPT + g] : 0.0f;
            a16[p]    = d ? ws[3 * NPT + g] : 0.0f;
            a26[p]    = d ? ws[4 * NPT + g] : 0.0f;
            a66[p]    = d ? ws[5 * NPT + g] : 0.0f;
            gs[p]     = d ? ws[6 * NPT + g] : 0.0f;
        }
    }

    // clamped halo staging coords (garbage-tolerant: trapezoid validity)
    const int rm = (r0 > 0) ? r0 - 1 : 0;
    const int rp = (r0 + 3 < TS) ? r0 + 3 : TS - 1;
    const int cm = (c0 > 0) ? c0 - 1 : 0;
    const int cp = (c0 + 3 < TS) ? c0 + 3 : TS - 1;

    const bool owned = (tx >= 4) && (tx < 12) && (ty >= 4) && (ty < 12);

    for (int s = 1; s <= KSTEPS; ++s) {
        float sig_t = sig[L * KSTEPS + s - 1];

        // publish current values
#pragma unroll
        for (int i = 0; i < 3; ++i)
#pragma unroll
            for (int j = 0; j < 3; ++j) {
                sx[r0 + i][c0 + j] = cx[i * 3 + j];
                sy[r0 + i][c0 + j] = cy[i * 3 + j];
            }
        __syncthreads();

        // assemble 5x5 neighborhoods (own 3x3 from regs + 16 halo from LDS)
        float vx[5][5], vy[5][5];
#pragma unroll
        for (int i = 0; i < 3; ++i)
#pragma unroll
            for (int j = 0; j < 3; ++j) {
                vx[i + 1][j + 1] = cx[i * 3 + j];
                vy[i + 1][j + 1] = cy[i * 3 + j];
            }
        // top & bottom rows
        vx[0][0] = sx[rm][cm];  vy[0][0] = sy[rm][cm];
        vx[4][0] = sx[rp][cm];  vy[4][0] = sy[rp][cm];
        vx[0][4] = sx[rm][cp];  vy[0][4] = sy[rm][cp];
        vx[4][4] = sx[rp][cp];  vy[4][4] = sy[rp][cp];
#pragma unroll
        for (int j = 0; j < 3; ++j) {
            vx[0][j + 1] = sx[rm][c0 + j];  vy[0][j + 1] = sy[rm][c0 + j];
            vx[4][j + 1] = sx[rp][c0 + j];  vy[4][j + 1] = sy[rp][c0 + j];
            vx[j + 1][0] = sx[r0 + j][cm];  vy[j + 1][0] = sy[r0 + j][cm];
            vx[j + 1][4] = sx[r0 + j][cp];  vy[j + 1][4] = sy[r0 + j][cp];
        }

        // update 9 points
#pragma unroll
        for (int i = 0; i < 3; ++i)
#pragma unroll
            for (int j = 0; j < 3; ++j) {
                int p = i * 3 + j;
                float xc = vx[i + 1][j + 1];
                float yc = vy[i + 1][j + 1];
                float cxx_x = vx[i][j + 1] + vx[i + 2][j + 1] - 2.0f * xc;
                float cyy_x = vx[i + 1][j] + vx[i + 1][j + 2] - 2.0f * xc;
                float cxy_x = 0.25f * (vx[i][j] - vx[i][j + 2] - vx[i + 2][j] + vx[i + 2][j + 2]);
                float cxx_y = vy[i][j + 1] + vy[i + 2][j + 1] - 2.0f * yc;
                float cyy_y = vy[i + 1][j] + vy[i + 1][j + 2] - 2.0f * yc;
                float cxy_y = 0.25f * (vy[i][j] - vy[i][j + 2] - vy[i + 2][j] + vy[i + 2][j + 2]);

                float lux = a11[p] * cxx_x + a66[p] * cyy_x + a12p66[p] * cxy_y
                          + 2.0f * a16[p] * cxy_x + a16[p] * cxx_y + a26[p] * cyy_y;
                float luy = a66[p] * cxx_y + a22[p] * cyy_y + a12p66[p] * cxy_x
                          + a16[p] * cxx_x + a26[p] * cyy_x + 2.0f * a26[p] * cxy_y;

                float nx = dom[p] ? (2.0f * xc - ox[p] + lux) : 0.0f;
                float ny = dom[p] ? (2.0f * yc - oy[p] + luy + sig_t * gs[p]) : 0.0f;
                ox[p] = xc; cx[p] = nx;
                oy[p] = yc; cy[p] = ny;
            }
        __syncthreads();

        // frame output at global t = L*12 + s - 1; t%4==3 <=> s%4==0
        if ((s & 3) == 0 && owned) {
            int f = 3 * L + (s >> 2) - 1;
            float* oux = out + (size_t)f * NPT;
            float* ouy = out + (size_t)(NFRAMES + f) * NPT;
#pragma unroll
            for (int p = 0; p < 9; ++p) {
                oux[gidx[p]] = cx[p];
                ouy[gidx[p]] = cy[p];
            }
        }
    }

    // write back the two newest levels (owned region only)
    if (owned) {
#pragma unroll
        for (int p = 0; p < 9; ++p) {
            int g = gidx[p];
            outCX[g] = cx[p];
            outCY[g] = cy[p];
            outOX[g] = ox[p];
            outOY[g] = oy[p];
        }
    }
}

extern "C" void kernel_launch(void* const* d_in, const int* in_sizes, int n_in,
                              void* d_out, int out_size, void* d_ws, size_t ws_size,
                              hipStream_t stream) {
    const float* lc11  = (const float*)d_in[0];
    const float* lc12  = (const float*)d_in[1];
    const float* lc16  = (const float*)d_in[2];
    const float* lc22  = (const float*)d_in[3];
    const float* lc26  = (const float*)d_in[4];
    const float* lc66  = (const float*)d_in[5];
    const float* gauss = (const float*)d_in[6];
    const float* sig   = (const float*)d_in[7];

    float* ws  = (float*)d_ws;
    float* out = (float*)d_out;

    setup_kernel<<<(NPT + 255) / 256, 256, 0, stream>>>(lc11, lc12, lc16, lc22,
                                                        lc26, lc66, gauss, ws);

    float* set0 = ws + 7 * NPT;   // CX,CY,OX,OY
    float* set1 = ws + 11 * NPT;

    dim3 grid(NXg / OWN, NYg / OWN);  // 16 x 16 = 256 blocks
    for (int L = 0; L < NLAUNCH; ++L) {
        float* inS  = (L & 1) ? set1 : set0;
        float* outS = (L & 1) ? set0 : set1;
        fused_kernel<<<grid, 256, 0, stream>>>(
            ws, sig,
            inS, inS + NPT, inS + 2 * NPT, inS + 3 * NPT,
            outS, outS + NPT, outS + 2 * NPT, outS + 3 * NPT,
            out, L);
    }
}

// Round 3
// 414.017 us; speedup vs baseline: 2.1471x; 1.1518x over previous
//
#include <hip/hip_runtime.h>

// Spatially varying anisotropic 2D elastic wave sim, 384x384, 192 steps.
// Round 2: time-tiled trapezoid fusion (K=12, 16 launches), refined:
//  - #pragma unroll 1 on step loop (keep body ~5KB, fits 32KB L1I)
//  - double-buffered LDS exchange -> ONE barrier per step (was 2)
//  - out-of-domain handled by zeroed coeffs (no per-point cndmask)
//  - cross-deriv via column-difference factorization (fewer VALU)
//  - per-field window assembly to cap register pressure

#define NXg 384
#define NYg 384
#define NPT (NXg * NYg)
#define NTs 192
#define NFRAMES 48

#define OWN 24
#define HALO 12
#define TS 48
#define KSTEPS 12
#define NLAUNCH 16

#define H_   1e-4
#define DT_  5e-9
#define RHO_ 1610.0

#define B11_LO 5e10f
#define B11_HI 2.5e11f
#define B22_LO 5e9f
#define B22_HI 5e10f
#define B12_LO 5e9f
#define B12_HI 5e10f
#define B16_LO 0.0f
#define B16_HI 6e10f
#define B26_LO 0.0f
#define B26_HI 2e10f
#define B66_LO 5e9f
#define B66_HI 3e10f

static __device__ __constant__ float kScale  = (float)(DT_ * DT_ / (H_ * H_) / RHO_);
static __device__ __constant__ float kSrcScl = (float)(DT_ * DT_ / RHO_);

__device__ __forceinline__ float clipf(float v, float lo, float hi) {
    return fminf(fmaxf(v, lo), hi);
}

// ws float layout: [0]=A11 [1]=A22 [2]=A12p66 [3]=A16 [4]=A26 [5]=A66 [6]=GS
// set0: [7..10]=CX,CY,OX,OY   set1: [11..14]

__global__ __launch_bounds__(256)
void setup_kernel(const float* __restrict__ lc11, const float* __restrict__ lc12,
                  const float* __restrict__ lc16, const float* __restrict__ lc22,
                  const float* __restrict__ lc26, const float* __restrict__ lc66,
                  const float* __restrict__ gauss, float* __restrict__ ws) {
    int i = blockIdx.x * blockDim.x + threadIdx.x;
    if (i >= NPT) return;
    float C11 = clipf(expf(lc11[i]), B11_LO, B11_HI);
    float C12 = clipf(expf(lc12[i]), B12_LO, B12_HI);
    float C16 = clipf(expf(lc16[i]), B16_LO, B16_HI);
    float C22 = clipf(expf(lc22[i]), B22_LO, B22_HI);
    float C26 = clipf(expf(lc26[i]), B26_LO, B26_HI);
    float C66 = clipf(expf(lc66[i]), B66_LO, B66_HI);
    float s = kScale;
    ws[0 * NPT + i] = C11 * s;
    ws[1 * NPT + i] = C22 * s;
    ws[2 * NPT + i] = (C12 + C66) * s;
    ws[3 * NPT + i] = C16 * s;
    ws[4 * NPT + i] = C26 * s;
    ws[5 * NPT + i] = C66 * s;
    ws[6 * NPT + i] = gauss[i] * kSrcScl;
    ws[7 * NPT + i]  = 0.0f;
    ws[8 * NPT + i]  = 0.0f;
    ws[9 * NPT + i]  = 0.0f;
    ws[10 * NPT + i] = 0.0f;
}

__global__ __launch_bounds__(256, 1)
void fused_kernel(const float* __restrict__ ws, const float* __restrict__ sig,
                  const float* __restrict__ inCX, const float* __restrict__ inCY,
                  const float* __restrict__ inOX, const float* __restrict__ inOY,
                  float* __restrict__ outCX, float* __restrict__ outCY,
                  float* __restrict__ outOX, float* __restrict__ outOY,
                  float* __restrict__ out, int L) {
    // double-buffered exchange surfaces: sb[buf][field][row][col]
    __shared__ float sb[2][2][TS][TS + 1];

    const int tid = threadIdx.x;
    const int tx = tid >> 4;
    const int ty = tid & 15;
    const int r0 = 3 * tx;
    const int c0 = 3 * ty;
    const int gx0 = blockIdx.y * OWN - HALO;
    const int gy0 = blockIdx.x * OWN - HALO;

    float cx[9], cy[9], ox[9], oy[9];
    float a11[9], a22[9], a12p66[9], a16[9], a26[9], a66[9], gs[9];
    int gidx[9];

#pragma unroll
    for (int i = 0; i < 3; ++i) {
#pragma unroll
        for (int j = 0; j < 3; ++j) {
            int p = i * 3 + j;
            int gx = gx0 + r0 + i;
            int gy = gy0 + c0 + j;
            bool d = (unsigned)gx < (unsigned)NXg && (unsigned)gy < (unsigned)NYg;
            int g = d ? gx * NYg + gy : 0;
            gidx[p] = g;
            cx[p] = d ? inCX[g] : 0.0f;
            cy[p] = d ? inCY[g] : 0.0f;
            ox[p] = d ? inOX[g] : 0.0f;
            oy[p] = d ? inOY[g] : 0.0f;
            // out-of-domain -> zero coeffs => point stays exactly 0, no cndmask
            a11[p]    = d ? ws[0 * NPT + g] : 0.0f;
            a22[p]    = d ? ws[1 * NPT + g] : 0.0f;
            a12p66[p] = d ? ws[2 * NPT + g] : 0.0f;
            a16[p]    = d ? ws[3 * NPT + g] : 0.0f;
            a26[p]    = d ? ws[4 * NPT + g] : 0.0f;
            a66[p]    = d ? ws[5 * NPT + g] : 0.0f;
            gs[p]     = d ? ws[6 * NPT + g] : 0.0f;
        }
    }

    // clamped halo coords (trapezoid garbage-tolerance at staging rim)
    const int rm = (r0 > 0) ? r0 - 1 : 0;
    const int rp = (r0 + 3 < TS) ? r0 + 3 : TS - 1;
    const int cm = (c0 > 0) ? c0 - 1 : 0;
    const int cp = (c0 + 3 < TS) ? c0 + 3 : TS - 1;

    const bool owned = (tx >= 4) && (tx < 12) && (ty >= 4) && (ty < 12);
    const int t0 = L * KSTEPS;

    // publish initial values into buffer 0
#pragma unroll
    for (int i = 0; i < 3; ++i)
#pragma unroll
        for (int j = 0; j < 3; ++j) {
            sb[0][0][r0 + i][c0 + j] = cx[i * 3 + j];
            sb[0][1][r0 + i][c0 + j] = cy[i * 3 + j];
        }
    __syncthreads();

#pragma unroll 1
    for (int s = 1; s <= KSTEPS; ++s) {
        const int cur = (s - 1) & 1;
        const float (*rx)[TS + 1] = sb[cur][0];
        const float (*ry)[TS + 1] = sb[cur][1];
        float (*wx)[TS + 1] = sb[cur ^ 1][0];
        float (*wy)[TS + 1] = sb[cur ^ 1][1];
        const float sig_t = sig[t0 + s - 1];

        float sxx_x[9], syy_x[9], sxy_x[9];
        float sxx_y[9], syy_y[9], sxy_y[9];

        // ---- field x: assemble 5x5 window, form stencil combos ----
        {
            float v[5][5];
#pragma unroll
            for (int i = 0; i < 3; ++i)
#pragma unroll
                for (int j = 0; j < 3; ++j)
                    v[i + 1][j + 1] = cx[i * 3 + j];
            v[0][0] = rx[rm][cm];  v[0][4] = rx[rm][cp];
            v[4][0] = rx[rp][cm];  v[4][4] = rx[rp][cp];
#pragma unroll
            for (int j = 0; j < 3; ++j) {
                v[0][j + 1] = rx[rm][c0 + j];
                v[4][j + 1] = rx[rp][c0 + j];
                v[j + 1][0] = rx[r0 + j][cm];
                v[j + 1][4] = rx[r0 + j][cp];
            }
            float dh[5][3];   // horizontal differences v[i][j+2]-v[i][j]
#pragma unroll
            for (int i = 0; i < 5; ++i)
#pragma unroll
                for (int j = 0; j < 3; ++j)
                    dh[i][j] = v[i][j + 2] - v[i][j];
#pragma unroll
            for (int i = 0; i < 3; ++i)
#pragma unroll
                for (int j = 0; j < 3; ++j) {
                    int p = i * 3 + j;
                    float c = v[i + 1][j + 1];
                    sxx_x[p] = v[i][j + 1] + v[i + 2][j + 1] - 2.0f * c;
                    syy_x[p] = v[i + 1][j] + v[i + 1][j + 2] - 2.0f * c;
                    sxy_x[p] = 0.25f * (dh[i + 2][j] - dh[i][j]);
                }
        }
        // ---- field y ----
        {
            float v[5][5];
#pragma unroll
            for (int i = 0; i < 3; ++i)
#pragma unroll
                for (int j = 0; j < 3; ++j)
                    v[i + 1][j + 1] = cy[i * 3 + j];
            v[0][0] = ry[rm][cm];  v[0][4] = ry[rm][cp];
            v[4][0] = ry[rp][cm];  v[4][4] = ry[rp][cp];
#pragma unroll
            for (int j = 0; j < 3; ++j) {
                v[0][j + 1] = ry[rm][c0 + j];
                v[4][j + 1] = ry[rp][c0 + j];
                v[j + 1][0] = ry[r0 + j][cm];
                v[j + 1][4] = ry[r0 + j][cp];
            }
            float dh[5][3];
#pragma unroll
            for (int i = 0; i < 5; ++i)
#pragma unroll
                for (int j = 0; j < 3; ++j)
                    dh[i][j] = v[i][j + 2] - v[i][j];
#pragma unroll
            for (int i = 0; i < 3; ++i)
#pragma unroll
                for (int j = 0; j < 3; ++j) {
                    int p = i * 3 + j;
                    float c = v[i + 1][j + 1];
                    sxx_y[p] = v[i][j + 1] + v[i + 2][j + 1] - 2.0f * c;
                    syy_y[p] = v[i + 1][j] + v[i + 1][j + 2] - 2.0f * c;
                    sxy_y[p] = 0.25f * (dh[i + 2][j] - dh[i][j]);
                }
        }

        // ---- update 9 points ----
#pragma unroll
        for (int p = 0; p < 9; ++p) {
            float lux = a11[p] * sxx_x[p] + a66[p] * syy_x[p] + a12p66[p] * sxy_y[p]
                      + a16[p] * (sxy_x[p] + sxy_x[p]) + a16[p] * sxx_y[p]
                      + a26[p] * syy_y[p];
            float luy = a66[p] * sxx_y[p] + a22[p] * syy_y[p] + a12p66[p] * sxy_x[p]
                      + a16[p] * sxx_x[p] + a26[p] * syy_x[p]
                      + a26[p] * (sxy_y[p] + sxy_y[p]);
            float nx = 2.0f * cx[p] - ox[p] + lux;
            float ny = 2.0f * cy[p] - oy[p] + luy + sig_t * gs[p];
            ox[p] = cx[p]; cx[p] = nx;
            oy[p] = cy[p]; cy[p] = ny;
        }

        // frame output at global t = t0 + s - 1; t%4==3 <=> s%4==0
        if ((s & 3) == 0 && owned) {
            int f = 3 * L + (s >> 2) - 1;
            float* oux = out + (size_t)f * NPT;
            float* ouy = out + (size_t)(NFRAMES + f) * NPT;
#pragma unroll
            for (int p = 0; p < 9; ++p) {
                oux[gidx[p]] = cx[p];
                ouy[gidx[p]] = cy[p];
            }
        }

        // publish new values into the other buffer; ONE barrier per step
#pragma unroll
        for (int i = 0; i < 3; ++i)
#pragma unroll
            for (int j = 0; j < 3; ++j) {
                wx[r0 + i][c0 + j] = cx[i * 3 + j];
                wy[r0 + i][c0 + j] = cy[i * 3 + j];
            }
        __syncthreads();
    }

    if (owned) {
#pragma unroll
        for (int p = 0; p < 9; ++p) {
            int g = gidx[p];
            outCX[g] = cx[p];
            outCY[g] = cy[p];
            outOX[g] = ox[p];
            outOY[g] = oy[p];
        }
    }
}

extern "C" void kernel_launch(void* const* d_in, const int* in_sizes, int n_in,
                              void* d_out, int out_size, void* d_ws, size_t ws_size,
                              hipStream_t stream) {
    const float* lc11  = (const float*)d_in[0];
    const float* lc12  = (const float*)d_in[1];
    const float* lc16  = (const float*)d_in[2];
    const float* lc22  = (const float*)d_in[3];
    const float* lc26  = (const float*)d_in[4];
    const float* lc66  = (const float*)d_in[5];
    const float* gauss = (const float*)d_in[6];
    const float* sig   = (const float*)d_in[7];

    float* ws  = (float*)d_ws;
    float* out = (float*)d_out;

    setup_kernel<<<(NPT + 255) / 256, 256, 0, stream>>>(lc11, lc12, lc16, lc22,
                                                        lc26, lc66, gauss, ws);

    float* set0 = ws + 7 * NPT;
    float* set1 = ws + 11 * NPT;

    dim3 grid(NXg / OWN, NYg / OWN);  // 16x16 = 256 blocks, 1 per CU
    for (int L = 0; L < NLAUNCH; ++L) {
        float* inS  = (L & 1) ? set1 : set0;
        float* outS = (L & 1) ? set0 : set1;
        fused_kernel<<<grid, 256, 0, stream>>>(
            ws, sig,
            inS, inS + NPT, inS + 2 * NPT, inS + 3 * NPT,
            outS, outS + NPT, outS + 2 * NPT, outS + 3 * NPT,
            out, L);
    }
}